// Round 7
// baseline (426.078 us; speedup 1.0000x reference)
//
#include <hip/hip_runtime.h>
#include <math.h>
#include <stdint.h>

// Problem constants: B=8, N=1024, C=1024, H=16, Dh=64
#define SEQ   1024
#define BATCH 8
#define CDIM  1024
#define HEADS 16
#define DHEAD 64

typedef __bf16 bf16;
typedef _Float16 f16;
typedef __attribute__((ext_vector_type(8))) __bf16 bf16x8;
typedef __attribute__((ext_vector_type(4))) __bf16 bf16x4;
typedef __attribute__((ext_vector_type(8))) _Float16 f16x8;
typedef __attribute__((ext_vector_type(4))) float f32x4;

// async global->LDS, 16B per lane. LDS dest = wave-uniform base + lane*16.
static __device__ __forceinline__ void gl16(const void* g, void* l) {
    __builtin_amdgcn_global_load_lds(
        (const __attribute__((address_space(1))) void*)(uintptr_t)g,
        (__attribute__((address_space(3))) void*)(uintptr_t)l,
        16, 0, 0);
}

// ===========================================================================
// split_bf16: x -> hi = bf16(x), lo = bf16(x - hi).  8 elems/thread/iter.
// ===========================================================================
__global__ __launch_bounds__(256)
void split_bf16(const float* __restrict__ in, bf16* __restrict__ hi,
                bf16* __restrict__ lo, int n8)
{
    int i = blockIdx.x * blockDim.x + threadIdx.x;
    const int stride = gridDim.x * blockDim.x;
    for (; i < n8; i += stride) {
        const f32x4 v0 = *(const f32x4*)(in + (size_t)i * 8);
        const f32x4 v1 = *(const f32x4*)(in + (size_t)i * 8 + 4);
        bf16x8 hv, lv;
#pragma unroll
        for (int j = 0; j < 4; j++) {
            const float f0 = v0[j], f1 = v1[j];
            const bf16 h0 = (bf16)f0, h1 = (bf16)f1;
            hv[j]     = h0;
            hv[j + 4] = h1;
            lv[j]     = (bf16)(f0 - (float)h0);
            lv[j + 4] = (bf16)(f1 - (float)h1);
        }
        *(bf16x8*)(hi + (size_t)i * 8) = hv;
        *(bf16x8*)(lo + (size_t)i * 8) = lv;
    }
}

// ===========================================================================
// Split-bf16 MFMA GEMM: C[M][Ncols] = A[M][K] @ W[Ncols][K]^T (+bias)
// acc += Ah*Bh + Ah*Bl + Al*Bh  (drops Al*Bl ~ 2^-16 rel). 128x128 tile,
// BK=32, 4 waves (2x2 of 64x64). Numerics identical to round-4/6 version.
// Staging now via global_load_lds width=16 (m97/m151 recipe): LDS layout
// [kg=4][row=128][8] is linear in (chunk=tid)*16B, i.e. wave-uniform base
// (wid*1024B) + lane*16B -- exactly the HW write pattern.
// MODE 0: row-major fp32 store to out0.
// MODE 1: QKV scatter as fp16: q (x0.125) -> qg[BH][N][64],
//         k -> kgp[BH][N][64],  v TRANSPOSED -> vgp[BH][64][N].
// ===========================================================================
template<int MODE>
__global__ __launch_bounds__(256, 4)
void gemm_mfma(const bf16* __restrict__ Ahg, const bf16* __restrict__ Alg,
               const bf16* __restrict__ Bhg, const bf16* __restrict__ Blg,
               const float* __restrict__ bias, float* __restrict__ out0,
               f16* __restrict__ qg, f16* __restrict__ kgp, f16* __restrict__ vgp,
               int M, int Ncols, int K)
{
    __shared__ bf16 Ah[4][128][8];
    __shared__ bf16 Al[4][128][8];
    __shared__ bf16 Bh[4][128][8];
    __shared__ bf16 Bl[4][128][8];

    const int tid  = threadIdx.x;
    const int m0   = blockIdx.y * 128;
    const int n0   = blockIdx.x * 128;
    const int wid  = tid >> 6;
    const int lane = tid & 63;
    const int wr   = (wid >> 1) * 64;
    const int wc   = (wid & 1) * 64;
    const int l16  = lane & 15;
    const int kgf  = lane >> 4;

    // chunk c0 = tid -> (kg0, row0); chunk c1 = tid+256 -> (kg0+2, row0)
    const int kg0 = tid >> 7, row0 = tid & 127;

    // per-lane global base addresses (chunk c0; c1 is +16 elements)
    const bf16* aH = Ahg + (size_t)(m0 + row0) * K + kg0 * 8;
    const bf16* aL = Alg + (size_t)(m0 + row0) * K + kg0 * 8;
    const bf16* bH = Bhg + (size_t)(n0 + row0) * K + kg0 * 8;
    const bf16* bL = Blg + (size_t)(n0 + row0) * K + kg0 * 8;

    // wave-uniform LDS bases (bytes): issue0 = wid*1024, issue1 = +4096
    char* ldsAh = (char*)&Ah[0][0][0] + (wid << 10);
    char* ldsAl = (char*)&Al[0][0][0] + (wid << 10);
    char* ldsBh = (char*)&Bh[0][0][0] + (wid << 10);
    char* ldsBl = (char*)&Bl[0][0][0] + (wid << 10);

    f32x4 acc[4][4];
#pragma unroll
    for (int i = 0; i < 4; i++)
#pragma unroll
        for (int j = 0; j < 4; j++) acc[i][j] = (f32x4)0.f;

    for (int kt = 0; kt < K; kt += 32) {
        __syncthreads();   // previous step's fragment reads complete; LDS free
        gl16(aH + kt,      ldsAh);
        gl16(aH + kt + 16, ldsAh + 4096);
        gl16(aL + kt,      ldsAl);
        gl16(aL + kt + 16, ldsAl + 4096);
        gl16(bH + kt,      ldsBh);
        gl16(bH + kt + 16, ldsBh + 4096);
        gl16(bL + kt,      ldsBl);
        gl16(bL + kt + 16, ldsBl + 4096);
        __syncthreads();   // drains vmcnt: staged tile visible

        bf16x8 fah[4], fal[4], fbh[4], fbl[4];
#pragma unroll
        for (int i = 0; i < 4; i++) {
            fah[i] = *(const bf16x8*)&Ah[kgf][wr + i * 16 + l16][0];
            fal[i] = *(const bf16x8*)&Al[kgf][wr + i * 16 + l16][0];
            fbh[i] = *(const bf16x8*)&Bh[kgf][wc + i * 16 + l16][0];
            fbl[i] = *(const bf16x8*)&Bl[kgf][wc + i * 16 + l16][0];
        }
#pragma unroll
        for (int mi = 0; mi < 4; mi++)
#pragma unroll
            for (int ni = 0; ni < 4; ni++) {
                acc[mi][ni] = __builtin_amdgcn_mfma_f32_16x16x32_bf16(
                    fah[mi], fbh[ni], acc[mi][ni], 0, 0, 0);
                acc[mi][ni] = __builtin_amdgcn_mfma_f32_16x16x32_bf16(
                    fah[mi], fbl[ni], acc[mi][ni], 0, 0, 0);
                acc[mi][ni] = __builtin_amdgcn_mfma_f32_16x16x32_bf16(
                    fal[mi], fbh[ni], acc[mi][ni], 0, 0, 0);
            }
    }

    // epilogue. D layout (verified r4): col = lane&15, row = (lane>>4)*4 + reg
#pragma unroll
    for (int ni = 0; ni < 4; ni++) {
        const int d  = n0 + wc + ni * 16 + l16;
        const float bv = bias[d];
        int s = 0, hh = 0, dh = 0;
        if (MODE == 1) {
            s  = d >> 10;
            hh = (d >> 6) & 15;
            dh = d & 63;
        }
#pragma unroll
        for (int mi = 0; mi < 4; mi++) {
            const int mbase = m0 + wr + mi * 16 + (lane >> 4) * 4;
#pragma unroll
            for (int r = 0; r < 4; r++) {
                const float v = acc[mi][ni][r] + bv;
                const int m = mbase + r;
                if (MODE == 0) {
                    out0[(size_t)m * Ncols + d] = v;
                } else {
                    const int b = m >> 10, n = m & 1023;
                    const size_t bho = (size_t)((b << 4) + hh) << 16;
                    if (s == 0)
                        qg[bho + ((size_t)n << 6) + dh] = (f16)(v * 0.125f);
                    else if (s == 1)
                        kgp[bho + ((size_t)n << 6) + dh] = (f16)v;
                    else
                        vgp[bho + ((size_t)dh << 10) + n] = (f16)v;
                }
            }
        }
    }
    (void)M;
}

// ===========================================================================
// MFMA flash attention (unchanged from round 6 -- verified passing).
// One block = 64 q-rows of one (b,h); 4 waves x 16 q-rows. fp16 MFMA for
// QK^T and PV, fp32 online softmax. Output: split-bf16 hi/lo to [B][N][C].
// ===========================================================================
__global__ __launch_bounds__(256, 4)
void attn_mfma(const f16* __restrict__ qf, const f16* __restrict__ kf,
               const f16* __restrict__ vtf, bf16* __restrict__ ohi,
               bf16* __restrict__ olo)
{
    __shared__ f16 Kl[8][64][8];    // [d/8][kcol][8]
    __shared__ f16 Vl[8][64][8];    // [k/8][drow][8]
    __shared__ f16 Pl[4][16][72];   // per-wave P: [wave][qrow][kcol], stride 72

    const int tid  = threadIdx.x;
    const int wid  = tid >> 6;
    const int lane = tid & 63;
    const int l16  = lane & 15;
    const int kg   = lane >> 4;      // 0..3
    const int bh   = blockIdx.y;
    const int q0   = blockIdx.x << 6;

    const size_t bhoff = (size_t)bh << 16;   // bh * 1024 * 64
    const f16* qb = qf  + bhoff;
    const f16* kb = kf  + bhoff;
    const f16* vb = vtf + bhoff;

    // Q fragments: row = q0+wid*16+l16, d = kg*8 + j (+32 for second half)
    f16x8 qfr[2];
    {
        const f16* qrow = qb + ((size_t)(q0 + wid * 16 + l16) << 6);
        qfr[0] = *(const f16x8*)(qrow + kg * 8);
        qfr[1] = *(const f16x8*)(qrow + 32 + kg * 8);
    }

    // staging assignment: 512 chunks of 16B per buffer, 2 per thread
    const int c0 = tid,        col0 = c0 & 63, slot0 = c0 >> 6;
    const int c1 = tid + 256,  col1 = c1 & 63, slot1 = c1 >> 6;

    float mrow[4], lrow[4];
    f32x4 accO[4];
#pragma unroll
    for (int r = 0; r < 4; r++) { mrow[r] = -INFINITY; lrow[r] = 0.f; }
#pragma unroll
    for (int t = 0; t < 4; t++) accO[t] = (f32x4)0.f;

    // prologue: k-tile 0 loads
    f16x8 rk0 = *(const f16x8*)(kb + ((size_t)col0 << 6) + slot0 * 8);
    f16x8 rk1 = *(const f16x8*)(kb + ((size_t)col1 << 6) + slot1 * 8);
    f16x8 rv0 = *(const f16x8*)(vb + ((size_t)col0 << 10) + slot0 * 8);
    f16x8 rv1 = *(const f16x8*)(vb + ((size_t)col1 << 10) + slot1 * 8);

    for (int kt = 0; kt < 16; kt++) {
        __syncthreads();   // previous iter's K/V fragment reads complete
        *(f16x8*)&Kl[slot0][col0][0] = rk0;
        *(f16x8*)&Kl[slot1][col1][0] = rk1;
        *(f16x8*)&Vl[slot0][col0][0] = rv0;
        *(f16x8*)&Vl[slot1][col1][0] = rv1;
        __syncthreads();

        // issue next tile's global loads; latency hides under compute
        if (kt < 15) {
            const int n1 = (kt + 1) << 6;
            rk0 = *(const f16x8*)(kb + ((size_t)(n1 + col0) << 6) + slot0 * 8);
            rk1 = *(const f16x8*)(kb + ((size_t)(n1 + col1) << 6) + slot1 * 8);
            rv0 = *(const f16x8*)(vb + ((size_t)col0 << 10) + n1 + slot0 * 8);
            rv1 = *(const f16x8*)(vb + ((size_t)col1 << 10) + n1 + slot1 * 8);
        }

        // ---- QK^T: wave's 16 rows x 64 cols, 4 col-tiles x 2 d-halves ----
        f32x4 accS[4];
#pragma unroll
        for (int t = 0; t < 4; t++) accS[t] = (f32x4)0.f;
#pragma unroll
        for (int t = 0; t < 4; t++) {
            const f16x8 kf0 = *(const f16x8*)&Kl[kg][t * 16 + l16][0];
            const f16x8 kf1 = *(const f16x8*)&Kl[4 + kg][t * 16 + l16][0];
            accS[t] = __builtin_amdgcn_mfma_f32_16x16x32_f16(qfr[0], kf0, accS[t], 0, 0, 0);
            accS[t] = __builtin_amdgcn_mfma_f32_16x16x32_f16(qfr[1], kf1, accS[t], 0, 0, 0);
        }

        // ---- online softmax; rows r -> q-row 4*kg + r, register-local ----
#pragma unroll
        for (int r = 0; r < 4; r++) {
            float sm = fmaxf(fmaxf(accS[0][r], accS[1][r]),
                             fmaxf(accS[2][r], accS[3][r]));
            sm = fmaxf(sm, __shfl_xor(sm, 1, 16));
            sm = fmaxf(sm, __shfl_xor(sm, 2, 16));
            sm = fmaxf(sm, __shfl_xor(sm, 4, 16));
            sm = fmaxf(sm, __shfl_xor(sm, 8, 16));
            const float mn = fmaxf(mrow[r], sm);
            const float al = __expf(mrow[r] - mn);
            float p0 = __expf(accS[0][r] - mn);
            float p1 = __expf(accS[1][r] - mn);
            float p2 = __expf(accS[2][r] - mn);
            float p3 = __expf(accS[3][r] - mn);
            float rs = (p0 + p1) + (p2 + p3);
            rs += __shfl_xor(rs, 1, 16);
            rs += __shfl_xor(rs, 2, 16);
            rs += __shfl_xor(rs, 4, 16);
            rs += __shfl_xor(rs, 8, 16);
            lrow[r] = lrow[r] * al + rs;
            mrow[r] = mn;
            accO[0][r] *= al;
            accO[1][r] *= al;
            accO[2][r] *= al;
            accO[3][r] *= al;
            const int prow = kg * 4 + r;
            Pl[wid][prow][l16]      = (f16)p0;
            Pl[wid][prow][16 + l16] = (f16)p1;
            Pl[wid][prow][32 + l16] = (f16)p2;
            Pl[wid][prow][48 + l16] = (f16)p3;
        }

        // ---- PV: O(16x64) += P(16x64) * V(64x64), via Vt fragments ----
#pragma unroll
        for (int h = 0; h < 2; h++) {
            const f16x8 pa = *(const f16x8*)&Pl[wid][l16][h * 32 + kg * 8];
#pragma unroll
            for (int t = 0; t < 4; t++) {
                const f16x8 vf = *(const f16x8*)&Vl[h * 4 + kg][t * 16 + l16][0];
                accO[t] = __builtin_amdgcn_mfma_f32_16x16x32_f16(pa, vf, accO[t], 0, 0, 0);
            }
        }
    }

    // ---- epilogue: normalize, split-bf16 store to [B][N][C] ----
    const int b = bh >> 4, hh = bh & 15;
#pragma unroll
    for (int r = 0; r < 4; r++) {
        const float inv = 1.0f / lrow[r];
        const int n = q0 + wid * 16 + kg * 4 + r;
        const size_t base = ((((size_t)b << 10) + n) << 10) + hh * 64;
#pragma unroll
        for (int t = 0; t < 4; t++) {
            const float o = accO[t][r] * inv;
            const bf16 oh = (bf16)o;
            ohi[base + t * 16 + l16] = oh;
            olo[base + t * 16 + l16] = (bf16)(o - (float)oh);
        }
    }
}

// ===========================================================================
// Fallback fp32 path (baseline, audited) — used only if ws_size < 96MB.
// ===========================================================================
#define TILE 128
#define KB   16
#define LSTR (TILE + 4)

template<int MODE>
__global__ __launch_bounds__(256, 2)
void gemm_bt(const float* __restrict__ A, const float* __restrict__ Bm,
             const float* __restrict__ bias, float* __restrict__ out0,
             float* __restrict__ qg, float* __restrict__ kg, float* __restrict__ vg,
             int M, int Ncols, int K)
{
    __shared__ float As[KB][LSTR];
    __shared__ float Bs[KB][LSTR];

    const int tid = threadIdx.x;
    const int tr  = tid >> 4;
    const int tc  = tid & 15;
    const int m0  = blockIdx.y * TILE;
    const int n0  = blockIdx.x * TILE;

    const int lrow = tid >> 2;
    const int lcol = (tid & 3) << 2;

    const float* Ap = A  + (size_t)(m0 + lrow) * K + lcol;
    const float* Bp = Bm + (size_t)(n0 + lrow) * K + lcol;
    const size_t rstep = (size_t)64 * K;

    float acc[8][8];
#pragma unroll
    for (int i = 0; i < 8; i++)
#pragma unroll
        for (int j = 0; j < 8; j++) acc[i][j] = 0.f;

    for (int kt = 0; kt < K; kt += KB) {
        float4 a0 = *(const float4*)(Ap + kt);
        float4 a1 = *(const float4*)(Ap + rstep + kt);
        float4 b0 = *(const float4*)(Bp + kt);
        float4 b1 = *(const float4*)(Bp + rstep + kt);
        __syncthreads();
        As[lcol + 0][lrow]      = a0.x;
        As[lcol + 1][lrow]      = a0.y;
        As[lcol + 2][lrow]      = a0.z;
        As[lcol + 3][lrow]      = a0.w;
        As[lcol + 0][lrow + 64] = a1.x;
        As[lcol + 1][lrow + 64] = a1.y;
        As[lcol + 2][lrow + 64] = a1.z;
        As[lcol + 3][lrow + 64] = a1.w;
        Bs[lcol + 0][lrow]      = b0.x;
        Bs[lcol + 1][lrow]      = b0.y;
        Bs[lcol + 2][lrow]      = b0.z;
        Bs[lcol + 3][lrow]      = b0.w;
        Bs[lcol + 0][lrow + 64] = b1.x;
        Bs[lcol + 1][lrow + 64] = b1.y;
        Bs[lcol + 2][lrow + 64] = b1.z;
        Bs[lcol + 3][lrow + 64] = b1.w;
        __syncthreads();
#pragma unroll
        for (int kk = 0; kk < KB; kk++) {
            float ar[8], br[8];
            *(float4*)&ar[0] = *(const float4*)&As[kk][tr << 2];
            *(float4*)&ar[4] = *(const float4*)&As[kk][64 + (tr << 2)];
            *(float4*)&br[0] = *(const float4*)&Bs[kk][tc << 2];
            *(float4*)&br[4] = *(const float4*)&Bs[kk][64 + (tc << 2)];
#pragma unroll
            for (int i = 0; i < 8; i++)
#pragma unroll
                for (int j = 0; j < 8; j++)
                    acc[i][j] = fmaf(ar[i], br[j], acc[i][j]);
        }
    }

#pragma unroll
    for (int rg = 0; rg < 2; rg++) {
#pragma unroll
        for (int ri = 0; ri < 4; ri++) {
            const int m = m0 + rg * 64 + (tr << 2) + ri;
#pragma unroll
            for (int cg = 0; cg < 2; cg++) {
                const int d = n0 + cg * 64 + (tc << 2);
                const float4 bb = *(const float4*)&bias[d];
                float v0 = acc[rg * 4 + ri][cg * 4 + 0] + bb.x;
                float v1 = acc[rg * 4 + ri][cg * 4 + 1] + bb.y;
                float v2 = acc[rg * 4 + ri][cg * 4 + 2] + bb.z;
                float v3 = acc[rg * 4 + ri][cg * 4 + 3] + bb.w;
                if (MODE == 0) {
                    *(float4*)&out0[(size_t)m * Ncols + d] = make_float4(v0, v1, v2, v3);
                } else {
                    const int s  = d >> 10;
                    const int h  = (d >> 6) & 15;
                    const int dh = d & 63;
                    const int b  = m >> 10;
                    const int n  = m & 1023;
                    float* dst = (s == 0) ? qg : ((s == 1) ? kg : vg);
                    if (s == 0) { v0 *= 0.125f; v1 *= 0.125f; v2 *= 0.125f; v3 *= 0.125f; }
                    const size_t idx = (((size_t)((b << 4) + h) << 10) + n) * 64 + dh;
                    *(float4*)&dst[idx] = make_float4(v0, v1, v2, v3);
                }
            }
        }
    }
}

__global__ __launch_bounds__(256, 2)
void attn_flash_f32(const float* __restrict__ qg, const float* __restrict__ kg,
                    const float* __restrict__ vg, float* __restrict__ og)
{
    __shared__ float Qs[64][68];
    __shared__ float KPs[64][68];
    __shared__ float Vs[64][68];

    const int tid = threadIdx.x;
    const int tr  = tid >> 4;
    const int tc  = tid & 15;
    const int bh  = blockIdx.y;
    const int q0  = blockIdx.x << 6;

    const float* qb = qg + ((size_t)bh * SEQ + q0) * DHEAD;
    const float* kb = kg + (size_t)bh * SEQ * DHEAD;
    const float* vb = vg + (size_t)bh * SEQ * DHEAD;

    const int lr = tid >> 4;
    const int lc = (tid & 15) << 2;

#pragma unroll
    for (int i = 0; i < 4; i++) {
        const int r = lr + (i << 4);
        float4 t = *(const float4*)(qb + r * 64 + lc);
        Qs[lc + 0][r] = t.x;
        Qs[lc + 1][r] = t.y;
        Qs[lc + 2][r] = t.z;
        Qs[lc + 3][r] = t.w;
    }

    float m[4], l[4], acc[4][4];
#pragma unroll
    for (int i = 0; i < 4; i++) {
        m[i] = -INFINITY; l[i] = 0.f;
#pragma unroll
        for (int j = 0; j < 4; j++) acc[i][j] = 0.f;
    }

    for (int kt = 0; kt < 16; kt++) {
        __syncthreads();
        const float* kbt = kb + (size_t)(kt << 6) * 64;
        const float* vbt = vb + (size_t)(kt << 6) * 64;
#pragma unroll
        for (int i = 0; i < 4; i++) {
            const int r = lr + (i << 4);
            float4 t = *(const float4*)(kbt + r * 64 + lc);
            KPs[lc + 0][r] = t.x;
            KPs[lc + 1][r] = t.y;
            KPs[lc + 2][r] = t.z;
            KPs[lc + 3][r] = t.w;
            float4 tv = *(const float4*)(vbt + r * 64 + lc);
            *(float4*)&Vs[r][lc] = tv;
        }
        __syncthreads();

        float s[4][4];
#pragma unroll
        for (int i = 0; i < 4; i++)
#pragma unroll
            for (int j = 0; j < 4; j++) s[i][j] = 0.f;
#pragma unroll 4
        for (int d = 0; d < 64; d++) {
            float qa[4], ka[4];
            *(float4*)qa = *(const float4*)&Qs[d][tr << 2];
            *(float4*)ka = *(const float4*)&KPs[d][tc << 2];
#pragma unroll
            for (int ri = 0; ri < 4; ri++)
#pragma unroll
                for (int ci = 0; ci < 4; ci++)
                    s[ri][ci] = fmaf(qa[ri], ka[ci], s[ri][ci]);
        }
        __syncthreads();

#pragma unroll
        for (int ri = 0; ri < 4; ri++) {
            float tm = fmaxf(fmaxf(s[ri][0], s[ri][1]), fmaxf(s[ri][2], s[ri][3]));
            tm = fmaxf(tm, __shfl_xor(tm, 1, 16));
            tm = fmaxf(tm, __shfl_xor(tm, 2, 16));
            tm = fmaxf(tm, __shfl_xor(tm, 4, 16));
            tm = fmaxf(tm, __shfl_xor(tm, 8, 16));
            const float mn = fmaxf(m[ri], tm);
            const float alpha = __expf(m[ri] - mn);
            const float p0 = __expf(s[ri][0] - mn);
            const float p1 = __expf(s[ri][1] - mn);
            const float p2 = __expf(s[ri][2] - mn);
            const float p3 = __expf(s[ri][3] - mn);
            float rs = (p0 + p1) + (p2 + p3);
            rs += __shfl_xor(rs, 1, 16);
            rs += __shfl_xor(rs, 2, 16);
            rs += __shfl_xor(rs, 4, 16);
            rs += __shfl_xor(rs, 8, 16);
            l[ri] = l[ri] * alpha + rs;
            m[ri] = mn;
            acc[ri][0] *= alpha; acc[ri][1] *= alpha;
            acc[ri][2] *= alpha; acc[ri][3] *= alpha;
            *(float4*)&KPs[(tr << 2) + ri][tc << 2] = make_float4(p0, p1, p2, p3);
        }
        __syncthreads();

#pragma unroll 4
        for (int c = 0; c < 64; c += 4) {
            float pr[4][4], vv[4][4];
            *(float4*)pr[0] = *(const float4*)&KPs[(tr << 2) + 0][c];
            *(float4*)pr[1] = *(const float4*)&KPs[(tr << 2) + 1][c];
            *(float4*)pr[2] = *(const float4*)&KPs[(tr << 2) + 2][c];
            *(float4*)pr[3] = *(const float4*)&KPs[(tr << 2) + 3][c];
            *(float4*)vv[0] = *(const float4*)&Vs[c + 0][tc << 2];
            *(float4*)vv[1] = *(const float4*)&Vs[c + 1][tc << 2];
            *(float4*)vv[2] = *(const float4*)&Vs[c + 2][tc << 2];
            *(float4*)vv[3] = *(const float4*)&Vs[c + 3][tc << 2];
#pragma unroll
            for (int ri = 0; ri < 4; ri++)
#pragma unroll
                for (int j = 0; j < 4; j++) {
                    float a = acc[ri][j];
                    a = fmaf(pr[ri][0], vv[0][j], a);
                    a = fmaf(pr[ri][1], vv[1][j], a);
                    a = fmaf(pr[ri][2], vv[2][j], a);
                    a = fmaf(pr[ri][3], vv[3][j], a);
                    acc[ri][j] = a;
                }
        }
    }

    const int b = bh >> 4, h = bh & 15;
#pragma unroll
    for (int ri = 0; ri < 4; ri++) {
        const float inv = 1.0f / l[ri];
        const int n = q0 + (tr << 2) + ri;
        const size_t idx = (((size_t)b * SEQ + n) << 10) + (h << 6) + (tc << 2);
        *(float4*)&og[idx] = make_float4(acc[ri][0] * inv, acc[ri][1] * inv,
                                         acc[ri][2] * inv, acc[ri][3] * inv);
    }
}

// ===========================================================================
extern "C" void kernel_launch(void* const* d_in, const int* in_sizes, int n_in,
                              void* d_out, int out_size, void* d_ws, size_t ws_size,
                              hipStream_t stream)
{
    const float* x     = (const float*)d_in[0];   // [8,1024,1024]
    const float* w_in  = (const float*)d_in[1];   // [3072,1024]
    const float* b_in  = (const float*)d_in[2];   // [3072]
    const float* w_out = (const float*)d_in[3];   // [1024,1024]
    const float* b_out = (const float*)d_in[4];   // [1024]
    float* out = (float*)d_out;                   // [8,1024,1024]
    (void)in_sizes; (void)n_in; (void)out_size;

    const size_t MB  = 1024 * 1024;
    const size_t per = (size_t)BATCH * HEADS * SEQ * DHEAD;  // 8M elements
    const int    M   = BATCH * SEQ;                          // 8192
    char* ws = (char*)d_ws;

    if (ws_size >= 96 * MB) {
        // --- MFMA path ---
        f16*  qf16  = (f16*)(ws + 0 * MB);    // 16MB [BH][N][64]
        f16*  kf16  = (f16*)(ws + 16 * MB);   // 16MB [BH][N][64]
        f16*  vtf16 = (f16*)(ws + 32 * MB);   // 16MB [BH][64][N]
        bf16* xhi   = (bf16*)(ws + 48 * MB);  // 16MB (dead after QKV GEMM)
        bf16* xlo   = (bf16*)(ws + 64 * MB);  // 16MB (dead after QKV GEMM)
        bf16* awhi  = xhi;                    // aliased: born after attention
        bf16* awlo  = xlo;
        bf16* wihi  = (bf16*)(ws + 80 * MB);  // 6MB
        bf16* wilo  = (bf16*)(ws + 86 * MB);  // 6MB
        bf16* wohi  = (bf16*)(ws + 92 * MB);  // 2MB
        bf16* wolo  = (bf16*)(ws + 94 * MB);  // 2MB -> 96MB total

        split_bf16<<<2048, 256, 0, stream>>>(x,     xhi,  xlo,  (int)(per / 8));
        split_bf16<<<1024, 256, 0, stream>>>(w_in,  wihi, wilo, 3 * CDIM * CDIM / 8);
        split_bf16<<<512,  256, 0, stream>>>(w_out, wohi, wolo, CDIM * CDIM / 8);

        gemm_mfma<1><<<dim3(3 * CDIM / 128, M / 128), 256, 0, stream>>>(
            xhi, xlo, wihi, wilo, b_in, nullptr, qf16, kf16, vtf16,
            M, 3 * CDIM, CDIM);

        attn_mfma<<<dim3(SEQ / 64, BATCH * HEADS), 256, 0, stream>>>(
            qf16, kf16, vtf16, awhi, awlo);

        gemm_mfma<0><<<dim3(CDIM / 128, M / 128), 256, 0, stream>>>(
            awhi, awlo, wohi, wolo, b_out, out, nullptr, nullptr, nullptr,
            M, CDIM, CDIM);
    } else {
        // --- fp32 fallback path (128MB) ---
        float* qws = (float*)d_ws;
        float* kws = qws + per;
        float* vws = kws + per;
        float* aws = vws + per;

        gemm_bt<1><<<dim3(3 * CDIM / TILE, M / TILE), 256, 0, stream>>>(
            x, w_in, b_in, nullptr, qws, kws, vws, M, 3 * CDIM, CDIM);

        attn_flash_f32<<<dim3(SEQ / 64, BATCH * HEADS), 256, 0, stream>>>(
            qws, kws, vws, aws);

        gemm_bt<0><<<dim3(CDIM / TILE, M / TILE), 256, 0, stream>>>(
            aws, w_out, b_out, out, nullptr, nullptr, nullptr, M, CDIM, CDIM);
    }
}

// Round 8
// 288.957 us; speedup vs baseline: 1.4745x; 1.4745x over previous
//
#include <hip/hip_runtime.h>
#include <math.h>
#include <stdint.h>

// Problem constants: B=8, N=1024, C=1024, H=16, Dh=64
#define SEQ   1024
#define BATCH 8
#define CDIM  1024
#define HEADS 16
#define DHEAD 64

typedef __bf16 bf16;
typedef _Float16 f16;
typedef __attribute__((ext_vector_type(8))) __bf16 bf16x8;
typedef __attribute__((ext_vector_type(8))) _Float16 f16x8;
typedef __attribute__((ext_vector_type(4))) float f32x4;

// async global->LDS, 16B per lane. LDS dest = wave-uniform base + lane*16.
static __device__ __forceinline__ void gl16(const void* g, void* l) {
    __builtin_amdgcn_global_load_lds(
        (const __attribute__((address_space(1))) void*)(uintptr_t)g,
        (__attribute__((address_space(3))) void*)(uintptr_t)l,
        16, 0, 0);
}

// ===========================================================================
// cvt_f16: fp32 -> fp16, 8 elems/thread/iter.
// ===========================================================================
__global__ __launch_bounds__(256)
void cvt_f16(const float* __restrict__ in, f16* __restrict__ out, int n8)
{
    int i = blockIdx.x * blockDim.x + threadIdx.x;
    const int stride = gridDim.x * blockDim.x;
    for (; i < n8; i += stride) {
        const f32x4 v0 = *(const f32x4*)(in + (size_t)i * 8);
        const f32x4 v1 = *(const f32x4*)(in + (size_t)i * 8 + 4);
        f16x8 o;
#pragma unroll
        for (int j = 0; j < 4; j++) {
            o[j]     = (f16)v0[j];
            o[j + 4] = (f16)v1[j];
        }
        *(f16x8*)(out + (size_t)i * 8) = o;
    }
}

// ===========================================================================
// fp16 MFMA GEMM: C[M][Ncols] = A[M][K] @ W[Ncols][K]^T (+bias)
// 128x128 tile, BK=32, 4 waves (2x2 of 64x64). fp32 accumulate.
// Staging via global_load_lds width=16; LDS [kg=4][row=128][8] f16 is linear
// in chunk(tid)*16B (wave-uniform base + lane*16) -- the HW write pattern.
// MODE 0: row-major fp32 store to out0.
// MODE 1: QKV scatter as fp16: q (x0.125) -> qg[BH][N][64],
//         k -> kgp[BH][N][64],  v TRANSPOSED -> vgp[BH][64][N].
// ===========================================================================
template<int MODE>
__global__ __launch_bounds__(256, 4)
void gemm_f16(const f16* __restrict__ Ag, const f16* __restrict__ Bg,
              const float* __restrict__ bias, float* __restrict__ out0,
              f16* __restrict__ qg, f16* __restrict__ kgp, f16* __restrict__ vgp,
              int M, int Ncols, int K)
{
    __shared__ f16 As[4][128][8];
    __shared__ f16 Bs[4][128][8];

    const int tid  = threadIdx.x;
    const int m0   = blockIdx.y * 128;
    const int n0   = blockIdx.x * 128;
    const int wid  = tid >> 6;
    const int lane = tid & 63;
    const int wr   = (wid >> 1) * 64;
    const int wc   = (wid & 1) * 64;
    const int l16  = lane & 15;
    const int kgf  = lane >> 4;

    // chunk c0 = tid -> (kg0, row0); chunk c1 = tid+256 -> (kg0+2, row0)
    const int kg0 = tid >> 7, row0 = tid & 127;

    const f16* aP = Ag + (size_t)(m0 + row0) * K + kg0 * 8;
    const f16* bP = Bg + (size_t)(n0 + row0) * K + kg0 * 8;

    // wave-uniform LDS bases (bytes): issue0 = wid*1024, issue1 = +4096
    char* ldsA = (char*)&As[0][0][0] + (wid << 10);
    char* ldsB = (char*)&Bs[0][0][0] + (wid << 10);

    f32x4 acc[4][4];
#pragma unroll
    for (int i = 0; i < 4; i++)
#pragma unroll
        for (int j = 0; j < 4; j++) acc[i][j] = (f32x4)0.f;

    for (int kt = 0; kt < K; kt += 32) {
        __syncthreads();   // previous step's fragment reads complete; LDS free
        gl16(aP + kt,      ldsA);
        gl16(aP + kt + 16, ldsA + 4096);
        gl16(bP + kt,      ldsB);
        gl16(bP + kt + 16, ldsB + 4096);
        __syncthreads();   // drains vmcnt: staged tile visible

        f16x8 fa[4], fb[4];
#pragma unroll
        for (int i = 0; i < 4; i++) {
            fa[i] = *(const f16x8*)&As[kgf][wr + i * 16 + l16][0];
            fb[i] = *(const f16x8*)&Bs[kgf][wc + i * 16 + l16][0];
        }
#pragma unroll
        for (int mi = 0; mi < 4; mi++)
#pragma unroll
            for (int ni = 0; ni < 4; ni++)
                acc[mi][ni] = __builtin_amdgcn_mfma_f32_16x16x32_f16(
                    fa[mi], fb[ni], acc[mi][ni], 0, 0, 0);
    }

    // epilogue. D layout (verified r4): col = lane&15, row = (lane>>4)*4 + reg
#pragma unroll
    for (int ni = 0; ni < 4; ni++) {
        const int d  = n0 + wc + ni * 16 + l16;
        const float bv = bias[d];
        int s = 0, hh = 0, dh = 0;
        if (MODE == 1) {
            s  = d >> 10;
            hh = (d >> 6) & 15;
            dh = d & 63;
        }
#pragma unroll
        for (int mi = 0; mi < 4; mi++) {
            const int mbase = m0 + wr + mi * 16 + (lane >> 4) * 4;
#pragma unroll
            for (int r = 0; r < 4; r++) {
                const float v = acc[mi][ni][r] + bv;
                const int m = mbase + r;
                if (MODE == 0) {
                    out0[(size_t)m * Ncols + d] = v;
                } else {
                    const int b = m >> 10, n = m & 1023;
                    const size_t bho = (size_t)((b << 4) + hh) << 16;
                    if (s == 0)
                        qg[bho + ((size_t)n << 6) + dh] = (f16)(v * 0.125f);
                    else if (s == 1)
                        kgp[bho + ((size_t)n << 6) + dh] = (f16)v;
                    else
                        vgp[bho + ((size_t)dh << 10) + n] = (f16)v;
                }
            }
        }
    }
    (void)M;
}

// ===========================================================================
// MFMA flash attention (structure verified r6). One block = 64 q-rows of one
// (b,h); 4 waves x 16 q-rows. fp16 MFMA QK^T/PV, fp32 online softmax.
// Output now plain fp16 O to [B][N][C] (consumed by fp16 out-proj GEMM).
// ===========================================================================
__global__ __launch_bounds__(256, 4)
void attn_mfma(const f16* __restrict__ qf, const f16* __restrict__ kf,
               const f16* __restrict__ vtf, f16* __restrict__ og)
{
    __shared__ f16 Kl[8][64][8];    // [d/8][kcol][8]
    __shared__ f16 Vl[8][64][8];    // [k/8][drow][8]
    __shared__ f16 Pl[4][16][72];   // per-wave P: [wave][qrow][kcol], stride 72

    const int tid  = threadIdx.x;
    const int wid  = tid >> 6;
    const int lane = tid & 63;
    const int l16  = lane & 15;
    const int kg   = lane >> 4;      // 0..3
    const int bh   = blockIdx.y;
    const int q0   = blockIdx.x << 6;

    const size_t bhoff = (size_t)bh << 16;   // bh * 1024 * 64
    const f16* qb = qf  + bhoff;
    const f16* kb = kf  + bhoff;
    const f16* vb = vtf + bhoff;

    // Q fragments: row = q0+wid*16+l16, d = kg*8 + j (+32 for second half)
    f16x8 qfr[2];
    {
        const f16* qrow = qb + ((size_t)(q0 + wid * 16 + l16) << 6);
        qfr[0] = *(const f16x8*)(qrow + kg * 8);
        qfr[1] = *(const f16x8*)(qrow + 32 + kg * 8);
    }

    // staging assignment: 512 chunks of 16B per buffer, 2 per thread
    const int c0 = tid,        col0 = c0 & 63, slot0 = c0 >> 6;
    const int c1 = tid + 256,  col1 = c1 & 63, slot1 = c1 >> 6;

    float mrow[4], lrow[4];
    f32x4 accO[4];
#pragma unroll
    for (int r = 0; r < 4; r++) { mrow[r] = -INFINITY; lrow[r] = 0.f; }
#pragma unroll
    for (int t = 0; t < 4; t++) accO[t] = (f32x4)0.f;

    // prologue: k-tile 0 loads
    f16x8 rk0 = *(const f16x8*)(kb + ((size_t)col0 << 6) + slot0 * 8);
    f16x8 rk1 = *(const f16x8*)(kb + ((size_t)col1 << 6) + slot1 * 8);
    f16x8 rv0 = *(const f16x8*)(vb + ((size_t)col0 << 10) + slot0 * 8);
    f16x8 rv1 = *(const f16x8*)(vb + ((size_t)col1 << 10) + slot1 * 8);

    for (int kt = 0; kt < 16; kt++) {
        __syncthreads();   // previous iter's K/V fragment reads complete
        *(f16x8*)&Kl[slot0][col0][0] = rk0;
        *(f16x8*)&Kl[slot1][col1][0] = rk1;
        *(f16x8*)&Vl[slot0][col0][0] = rv0;
        *(f16x8*)&Vl[slot1][col1][0] = rv1;
        __syncthreads();

        // issue next tile's global loads; latency hides under compute
        if (kt < 15) {
            const int n1 = (kt + 1) << 6;
            rk0 = *(const f16x8*)(kb + ((size_t)(n1 + col0) << 6) + slot0 * 8);
            rk1 = *(const f16x8*)(kb + ((size_t)(n1 + col1) << 6) + slot1 * 8);
            rv0 = *(const f16x8*)(vb + ((size_t)col0 << 10) + n1 + slot0 * 8);
            rv1 = *(const f16x8*)(vb + ((size_t)col1 << 10) + n1 + slot1 * 8);
        }

        // ---- QK^T: wave's 16 rows x 64 cols, 4 col-tiles x 2 d-halves ----
        f32x4 accS[4];
#pragma unroll
        for (int t = 0; t < 4; t++) accS[t] = (f32x4)0.f;
#pragma unroll
        for (int t = 0; t < 4; t++) {
            const f16x8 kf0 = *(const f16x8*)&Kl[kg][t * 16 + l16][0];
            const f16x8 kf1 = *(const f16x8*)&Kl[4 + kg][t * 16 + l16][0];
            accS[t] = __builtin_amdgcn_mfma_f32_16x16x32_f16(qfr[0], kf0, accS[t], 0, 0, 0);
            accS[t] = __builtin_amdgcn_mfma_f32_16x16x32_f16(qfr[1], kf1, accS[t], 0, 0, 0);
        }

        // ---- online softmax; rows r -> q-row 4*kg + r, register-local ----
#pragma unroll
        for (int r = 0; r < 4; r++) {
            float sm = fmaxf(fmaxf(accS[0][r], accS[1][r]),
                             fmaxf(accS[2][r], accS[3][r]));
            sm = fmaxf(sm, __shfl_xor(sm, 1, 16));
            sm = fmaxf(sm, __shfl_xor(sm, 2, 16));
            sm = fmaxf(sm, __shfl_xor(sm, 4, 16));
            sm = fmaxf(sm, __shfl_xor(sm, 8, 16));
            const float mn = fmaxf(mrow[r], sm);
            const float al = __expf(mrow[r] - mn);
            float p0 = __expf(accS[0][r] - mn);
            float p1 = __expf(accS[1][r] - mn);
            float p2 = __expf(accS[2][r] - mn);
            float p3 = __expf(accS[3][r] - mn);
            float rs = (p0 + p1) + (p2 + p3);
            rs += __shfl_xor(rs, 1, 16);
            rs += __shfl_xor(rs, 2, 16);
            rs += __shfl_xor(rs, 4, 16);
            rs += __shfl_xor(rs, 8, 16);
            lrow[r] = lrow[r] * al + rs;
            mrow[r] = mn;
            accO[0][r] *= al;
            accO[1][r] *= al;
            accO[2][r] *= al;
            accO[3][r] *= al;
            const int prow = kg * 4 + r;
            Pl[wid][prow][l16]      = (f16)p0;
            Pl[wid][prow][16 + l16] = (f16)p1;
            Pl[wid][prow][32 + l16] = (f16)p2;
            Pl[wid][prow][48 + l16] = (f16)p3;
        }

        // ---- PV: O(16x64) += P(16x64) * V(64x64), via Vt fragments ----
#pragma unroll
        for (int h = 0; h < 2; h++) {
            const f16x8 pa = *(const f16x8*)&Pl[wid][l16][h * 32 + kg * 8];
#pragma unroll
            for (int t = 0; t < 4; t++) {
                const f16x8 vf = *(const f16x8*)&Vl[h * 4 + kg][t * 16 + l16][0];
                accO[t] = __builtin_amdgcn_mfma_f32_16x16x32_f16(pa, vf, accO[t], 0, 0, 0);
            }
        }
    }

    // ---- epilogue: normalize, fp16 store to [B][N][C] ----
    const int b = bh >> 4, hh = bh & 15;
#pragma unroll
    for (int r = 0; r < 4; r++) {
        const float inv = 1.0f / lrow[r];
        const int n = q0 + wid * 16 + kg * 4 + r;
        const size_t base = ((((size_t)b << 10) + n) << 10) + hh * 64;
#pragma unroll
        for (int t = 0; t < 4; t++)
            og[base + t * 16 + l16] = (f16)(accO[t][r] * inv);
    }
}

// ===========================================================================
// Fallback fp32 path (baseline, audited) — used only if ws_size < 96MB.
// ===========================================================================
#define TILE 128
#define KB   16
#define LSTR (TILE + 4)

template<int MODE>
__global__ __launch_bounds__(256, 2)
void gemm_bt(const float* __restrict__ A, const float* __restrict__ Bm,
             const float* __restrict__ bias, float* __restrict__ out0,
             float* __restrict__ qg, float* __restrict__ kg, float* __restrict__ vg,
             int M, int Ncols, int K)
{
    __shared__ float As[KB][LSTR];
    __shared__ float Bs[KB][LSTR];

    const int tid = threadIdx.x;
    const int tr  = tid >> 4;
    const int tc  = tid & 15;
    const int m0  = blockIdx.y * TILE;
    const int n0  = blockIdx.x * TILE;

    const int lrow = tid >> 2;
    const int lcol = (tid & 3) << 2;

    const float* Ap = A  + (size_t)(m0 + lrow) * K + lcol;
    const float* Bp = Bm + (size_t)(n0 + lrow) * K + lcol;
    const size_t rstep = (size_t)64 * K;

    float acc[8][8];
#pragma unroll
    for (int i = 0; i < 8; i++)
#pragma unroll
        for (int j = 0; j < 8; j++) acc[i][j] = 0.f;

    for (int kt = 0; kt < K; kt += KB) {
        float4 a0 = *(const float4*)(Ap + kt);
        float4 a1 = *(const float4*)(Ap + rstep + kt);
        float4 b0 = *(const float4*)(Bp + kt);
        float4 b1 = *(const float4*)(Bp + rstep + kt);
        __syncthreads();
        As[lcol + 0][lrow]      = a0.x;
        As[lcol + 1][lrow]      = a0.y;
        As[lcol + 2][lrow]      = a0.z;
        As[lcol + 3][lrow]      = a0.w;
        As[lcol + 0][lrow + 64] = a1.x;
        As[lcol + 1][lrow + 64] = a1.y;
        As[lcol + 2][lrow + 64] = a1.z;
        As[lcol + 3][lrow + 64] = a1.w;
        Bs[lcol + 0][lrow]      = b0.x;
        Bs[lcol + 1][lrow]      = b0.y;
        Bs[lcol + 2][lrow]      = b0.z;
        Bs[lcol + 3][lrow]      = b0.w;
        Bs[lcol + 0][lrow + 64] = b1.x;
        Bs[lcol + 1][lrow + 64] = b1.y;
        Bs[lcol + 2][lrow + 64] = b1.z;
        Bs[lcol + 3][lrow + 64] = b1.w;
        __syncthreads();
#pragma unroll
        for (int kk = 0; kk < KB; kk++) {
            float ar[8], br[8];
            *(float4*)&ar[0] = *(const float4*)&As[kk][tr << 2];
            *(float4*)&ar[4] = *(const float4*)&As[kk][64 + (tr << 2)];
            *(float4*)&br[0] = *(const float4*)&Bs[kk][tc << 2];
            *(float4*)&br[4] = *(const float4*)&Bs[kk][64 + (tc << 2)];
#pragma unroll
            for (int i = 0; i < 8; i++)
#pragma unroll
                for (int j = 0; j < 8; j++)
                    acc[i][j] = fmaf(ar[i], br[j], acc[i][j]);
        }
    }

#pragma unroll
    for (int rg = 0; rg < 2; rg++) {
#pragma unroll
        for (int ri = 0; ri < 4; ri++) {
            const int m = m0 + rg * 64 + (tr << 2) + ri;
#pragma unroll
            for (int cg = 0; cg < 2; cg++) {
                const int d = n0 + cg * 64 + (tc << 2);
                const float4 bb = *(const float4*)&bias[d];
                float v0 = acc[rg * 4 + ri][cg * 4 + 0] + bb.x;
                float v1 = acc[rg * 4 + ri][cg * 4 + 1] + bb.y;
                float v2 = acc[rg * 4 + ri][cg * 4 + 2] + bb.z;
                float v3 = acc[rg * 4 + ri][cg * 4 + 3] + bb.w;
                if (MODE == 0) {
                    *(float4*)&out0[(size_t)m * Ncols + d] = make_float4(v0, v1, v2, v3);
                } else {
                    const int s  = d >> 10;
                    const int h  = (d >> 6) & 15;
                    const int dh = d & 63;
                    const int b  = m >> 10;
                    const int n  = m & 1023;
                    float* dst = (s == 0) ? qg : ((s == 1) ? kg : vg);
                    if (s == 0) { v0 *= 0.125f; v1 *= 0.125f; v2 *= 0.125f; v3 *= 0.125f; }
                    const size_t idx = (((size_t)((b << 4) + h) << 10) + n) * 64 + dh;
                    *(float4*)&dst[idx] = make_float4(v0, v1, v2, v3);
                }
            }
        }
    }
}

__global__ __launch_bounds__(256, 2)
void attn_flash_f32(const float* __restrict__ qg, const float* __restrict__ kg,
                    const float* __restrict__ vg, float* __restrict__ og)
{
    __shared__ float Qs[64][68];
    __shared__ float KPs[64][68];
    __shared__ float Vs[64][68];

    const int tid = threadIdx.x;
    const int tr  = tid >> 4;
    const int tc  = tid & 15;
    const int bh  = blockIdx.y;
    const int q0  = blockIdx.x << 6;

    const float* qb = qg + ((size_t)bh * SEQ + q0) * DHEAD;
    const float* kb = kg + (size_t)bh * SEQ * DHEAD;
    const float* vb = vg + (size_t)bh * SEQ * DHEAD;

    const int lr = tid >> 4;
    const int lc = (tid & 15) << 2;

#pragma unroll
    for (int i = 0; i < 4; i++) {
        const int r = lr + (i << 4);
        float4 t = *(const float4*)(qb + r * 64 + lc);
        Qs[lc + 0][r] = t.x;
        Qs[lc + 1][r] = t.y;
        Qs[lc + 2][r] = t.z;
        Qs[lc + 3][r] = t.w;
    }

    float m[4], l[4], acc[4][4];
#pragma unroll
    for (int i = 0; i < 4; i++) {
        m[i] = -INFINITY; l[i] = 0.f;
#pragma unroll
        for (int j = 0; j < 4; j++) acc[i][j] = 0.f;
    }

    for (int kt = 0; kt < 16; kt++) {
        __syncthreads();
        const float* kbt = kb + (size_t)(kt << 6) * 64;
        const float* vbt = vb + (size_t)(kt << 6) * 64;
#pragma unroll
        for (int i = 0; i < 4; i++) {
            const int r = lr + (i << 4);
            float4 t = *(const float4*)(kbt + r * 64 + lc);
            KPs[lc + 0][r] = t.x;
            KPs[lc + 1][r] = t.y;
            KPs[lc + 2][r] = t.z;
            KPs[lc + 3][r] = t.w;
            float4 tv = *(const float4*)(vbt + r * 64 + lc);
            *(float4*)&Vs[r][lc] = tv;
        }
        __syncthreads();

        float s[4][4];
#pragma unroll
        for (int i = 0; i < 4; i++)
#pragma unroll
            for (int j = 0; j < 4; j++) s[i][j] = 0.f;
#pragma unroll 4
        for (int d = 0; d < 64; d++) {
            float qa[4], ka[4];
            *(float4*)qa = *(const float4*)&Qs[d][tr << 2];
            *(float4*)ka = *(const float4*)&KPs[d][tc << 2];
#pragma unroll
            for (int ri = 0; ri < 4; ri++)
#pragma unroll
                for (int ci = 0; ci < 4; ci++)
                    s[ri][ci] = fmaf(qa[ri], ka[ci], s[ri][ci]);
        }
        __syncthreads();

#pragma unroll
        for (int ri = 0; ri < 4; ri++) {
            float tm = fmaxf(fmaxf(s[ri][0], s[ri][1]), fmaxf(s[ri][2], s[ri][3]));
            tm = fmaxf(tm, __shfl_xor(tm, 1, 16));
            tm = fmaxf(tm, __shfl_xor(tm, 2, 16));
            tm = fmaxf(tm, __shfl_xor(tm, 4, 16));
            tm = fmaxf(tm, __shfl_xor(tm, 8, 16));
            const float mn = fmaxf(m[ri], tm);
            const float alpha = __expf(m[ri] - mn);
            const float p0 = __expf(s[ri][0] - mn);
            const float p1 = __expf(s[ri][1] - mn);
            const float p2 = __expf(s[ri][2] - mn);
            const float p3 = __expf(s[ri][3] - mn);
            float rs = (p0 + p1) + (p2 + p3);
            rs += __shfl_xor(rs, 1, 16);
            rs += __shfl_xor(rs, 2, 16);
            rs += __shfl_xor(rs, 4, 16);
            rs += __shfl_xor(rs, 8, 16);
            l[ri] = l[ri] * alpha + rs;
            m[ri] = mn;
            acc[ri][0] *= alpha; acc[ri][1] *= alpha;
            acc[ri][2] *= alpha; acc[ri][3] *= alpha;
            *(float4*)&KPs[(tr << 2) + ri][tc << 2] = make_float4(p0, p1, p2, p3);
        }
        __syncthreads();

#pragma unroll 4
        for (int c = 0; c < 64; c += 4) {
            float pr[4][4], vv[4][4];
            *(float4*)pr[0] = *(const float4*)&KPs[(tr << 2) + 0][c];
            *(float4*)pr[1] = *(const float4*)&KPs[(tr << 2) + 1][c];
            *(float4*)pr[2] = *(const float4*)&KPs[(tr << 2) + 2][c];
            *(float4*)pr[3] = *(const float4*)&KPs[(tr << 2) + 3][c];
            *(float4*)vv[0] = *(const float4*)&Vs[c + 0][tc << 2];
            *(float4*)vv[1] = *(const float4*)&Vs[c + 1][tc << 2];
            *(float4*)vv[2] = *(const float4*)&Vs[c + 2][tc << 2];
            *(float4*)vv[3] = *(const float4*)&Vs[c + 3][tc << 2];
#pragma unroll
            for (int ri = 0; ri < 4; ri++)
#pragma unroll
                for (int j = 0; j < 4; j++) {
                    float a = acc[ri][j];
                    a = fmaf(pr[ri][0], vv[0][j], a);
                    a = fmaf(pr[ri][1], vv[1][j], a);
                    a = fmaf(pr[ri][2], vv[2][j], a);
                    a = fmaf(pr[ri][3], vv[3][j], a);
                    acc[ri][j] = a;
                }
        }
    }

    const int b = bh >> 4, h = bh & 15;
#pragma unroll
    for (int ri = 0; ri < 4; ri++) {
        const float inv = 1.0f / l[ri];
        const int n = q0 + (tr << 2) + ri;
        const size_t idx = (((size_t)b * SEQ + n) << 10) + (h << 6) + (tc << 2);
        *(float4*)&og[idx] = make_float4(acc[ri][0] * inv, acc[ri][1] * inv,
                                         acc[ri][2] * inv, acc[ri][3] * inv);
    }
}

// ===========================================================================
extern "C" void kernel_launch(void* const* d_in, const int* in_sizes, int n_in,
                              void* d_out, int out_size, void* d_ws, size_t ws_size,
                              hipStream_t stream)
{
    const float* x     = (const float*)d_in[0];   // [8,1024,1024]
    const float* w_in  = (const float*)d_in[1];   // [3072,1024]
    const float* b_in  = (const float*)d_in[2];   // [3072]
    const float* w_out = (const float*)d_in[3];   // [1024,1024]
    const float* b_out = (const float*)d_in[4];   // [1024]
    float* out = (float*)d_out;                   // [8,1024,1024]
    (void)in_sizes; (void)n_in; (void)out_size;

    const size_t MB  = 1024 * 1024;
    const size_t per = (size_t)BATCH * HEADS * SEQ * DHEAD;  // 8M elements
    const int    M   = BATCH * SEQ;                          // 8192
    char* ws = (char*)d_ws;

    if (ws_size >= 96 * MB) {
        // --- fp16 MFMA path ---
        f16* qf16  = (f16*)(ws + 0 * MB);    // 16MB [BH][N][64]
        f16* kf16  = (f16*)(ws + 16 * MB);   // 16MB [BH][N][64]
        f16* vtf16 = (f16*)(ws + 32 * MB);   // 16MB [BH][64][N]
        f16* xf16  = (f16*)(ws + 48 * MB);   // 16MB (dead after QKV GEMM)
        f16* of16  = xf16;                   // aliased: born after attention
        f16* wif16 = (f16*)(ws + 64 * MB);   // 6MB
        f16* wof16 = (f16*)(ws + 70 * MB);   // 2MB -> 72MB total

        cvt_f16<<<2048, 256, 0, stream>>>(x,     xf16,  (int)(per / 8));
        cvt_f16<<<1024, 256, 0, stream>>>(w_in,  wif16, 3 * CDIM * CDIM / 8);
        cvt_f16<<<512,  256, 0, stream>>>(w_out, wof16, CDIM * CDIM / 8);

        gemm_f16<1><<<dim3(3 * CDIM / 128, M / 128), 256, 0, stream>>>(
            xf16, wif16, b_in, nullptr, qf16, kf16, vtf16, M, 3 * CDIM, CDIM);

        attn_mfma<<<dim3(SEQ / 64, BATCH * HEADS), 256, 0, stream>>>(
            qf16, kf16, vtf16, of16);

        gemm_f16<0><<<dim3(CDIM / 128, M / 128), 256, 0, stream>>>(
            of16, wof16, b_out, out, nullptr, nullptr, nullptr, M, CDIM, CDIM);
    } else {
        // --- fp32 fallback path (128MB) ---
        float* qws = (float*)d_ws;
        float* kws = qws + per;
        float* vws = kws + per;
        float* aws = vws + per;

        gemm_bt<1><<<dim3(3 * CDIM / TILE, M / TILE), 256, 0, stream>>>(
            x, w_in, b_in, nullptr, qws, kws, vws, M, 3 * CDIM, CDIM);

        attn_flash_f32<<<dim3(SEQ / 64, BATCH * HEADS), 256, 0, stream>>>(
            qws, kws, vws, aws);

        gemm_bt<0><<<dim3(CDIM / TILE, M / TILE), 256, 0, stream>>>(
            aws, w_out, b_out, out, nullptr, nullptr, nullptr, M, CDIM, CDIM);
    }
}

// Round 9
// 285.406 us; speedup vs baseline: 1.4929x; 1.0124x over previous
//
#include <hip/hip_runtime.h>
#include <math.h>
#include <stdint.h>

// Problem constants: B=8, N=1024, C=1024, H=16, Dh=64
#define SEQ   1024
#define BATCH 8
#define CDIM  1024
#define HEADS 16
#define DHEAD 64

typedef __bf16 bf16;
typedef _Float16 f16;
typedef __attribute__((ext_vector_type(8))) _Float16 f16x8;
typedef __attribute__((ext_vector_type(4))) float f32x4;

// async global->LDS, 16B per lane. LDS dest = wave-uniform base + lane*16.
static __device__ __forceinline__ void gl16(const void* g, void* l) {
    __builtin_amdgcn_global_load_lds(
        (const __attribute__((address_space(1))) void*)(uintptr_t)g,
        (__attribute__((address_space(3))) void*)(uintptr_t)l,
        16, 0, 0);
}

// ===========================================================================
// cvt_f16: fp32 -> fp16, 8 elems/thread/iter.
// ===========================================================================
__global__ __launch_bounds__(256)
void cvt_f16(const float* __restrict__ in, f16* __restrict__ out, int n8)
{
    int i = blockIdx.x * blockDim.x + threadIdx.x;
    const int stride = gridDim.x * blockDim.x;
    for (; i < n8; i += stride) {
        const f32x4 v0 = *(const f32x4*)(in + (size_t)i * 8);
        const f32x4 v1 = *(const f32x4*)(in + (size_t)i * 8 + 4);
        f16x8 o;
#pragma unroll
        for (int j = 0; j < 4; j++) {
            o[j]     = (f16)v0[j];
            o[j + 4] = (f16)v1[j];
        }
        *(f16x8*)(out + (size_t)i * 8) = o;
    }
}

// ===========================================================================
// fp16 MFMA GEMM, 2-phase double-buffered (T3-lite) + XCD chunk swizzle.
// C[M][Ncols] = A[M][K] @ W[Ncols][K]^T (+bias). 128x128 tile, BK=32,
// 4 waves (2x2 of 64x64), fp32 accumulate.
// K-loop: { STAGE(buf^1, t+1) ; compute buf ; __syncthreads() } -- the
// end-of-iter barrier drains vmcnt, so next-tile loads fly during compute.
// MODE 0: row-major fp32 store. MODE 1: QKV scatter as fp16 (q x0.125 ->
// qg[BH][N][64], k -> kgp[BH][N][64], v transposed -> vgp[BH][64][N]).
// ===========================================================================
template<int MODE>
__global__ __launch_bounds__(256, 4)
void gemm_f16(const f16* __restrict__ Ag, const f16* __restrict__ Bg,
              const float* __restrict__ bias, float* __restrict__ out0,
              f16* __restrict__ qg, f16* __restrict__ kgp, f16* __restrict__ vgp,
              int M, int Ncols, int K)
{
    __shared__ f16 As[2][4][128][8];
    __shared__ f16 Bs[2][4][128][8];

    // bijective XCD chunk swizzle (nwg % 8 == 0 for both call sites):
    // consecutive linear ids within one XCD chunk share A row-panels -> L2 hits
    const int nx   = gridDim.x;
    const int nwg  = nx * gridDim.y;
    const int lin  = blockIdx.y * nx + blockIdx.x;
    const int cpx  = nwg >> 3;
    const int swz  = (lin & 7) * cpx + (lin >> 3);
    const int m0   = (swz / nx) * 128;
    const int n0   = (swz % nx) * 128;

    const int tid  = threadIdx.x;
    const int wid  = tid >> 6;
    const int lane = tid & 63;
    const int wr   = (wid >> 1) * 64;
    const int wc   = (wid & 1) * 64;
    const int l16  = lane & 15;
    const int kgf  = lane >> 4;

    // staging: chunk c0 = tid -> (kg0, row0); chunk c1 = tid+256 -> (kg0+2, row0)
    const int kg0 = tid >> 7, row0 = tid & 127;
    const f16* aP = Ag + (size_t)(m0 + row0) * K + kg0 * 8;
    const f16* bP = Bg + (size_t)(n0 + row0) * K + kg0 * 8;
    const int loff = wid << 10;   // wave-uniform byte offset within a buffer

    f32x4 acc[4][4];
#pragma unroll
    for (int i = 0; i < 4; i++)
#pragma unroll
        for (int j = 0; j < 4; j++) acc[i][j] = (f32x4)0.f;

    // prologue: stage tile 0 into buffer 0
    gl16(aP,      (char*)&As[0][0][0][0] + loff);
    gl16(aP + 16, (char*)&As[0][0][0][0] + loff + 4096);
    gl16(bP,      (char*)&Bs[0][0][0][0] + loff);
    gl16(bP + 16, (char*)&Bs[0][0][0][0] + loff + 4096);
    __syncthreads();   // drain: tile 0 visible

    const int T = K >> 5;
    for (int t = 0; t < T; t++) {
        const int cur = t & 1;
        // issue next tile's async loads into the other buffer; they complete
        // under this iteration's ds_read+MFMA, drained by the barrier below.
        if (t + 1 < T) {
            const int nxt = cur ^ 1;
            const int kn  = (t + 1) << 5;
            gl16(aP + kn,      (char*)&As[nxt][0][0][0] + loff);
            gl16(aP + kn + 16, (char*)&As[nxt][0][0][0] + loff + 4096);
            gl16(bP + kn,      (char*)&Bs[nxt][0][0][0] + loff);
            gl16(bP + kn + 16, (char*)&Bs[nxt][0][0][0] + loff + 4096);
        }

        f16x8 fa[4], fb[4];
#pragma unroll
        for (int i = 0; i < 4; i++) {
            fa[i] = *(const f16x8*)&As[cur][kgf][wr + i * 16 + l16][0];
            fb[i] = *(const f16x8*)&Bs[cur][kgf][wc + i * 16 + l16][0];
        }
#pragma unroll
        for (int mi = 0; mi < 4; mi++)
#pragma unroll
            for (int ni = 0; ni < 4; ni++)
                acc[mi][ni] = __builtin_amdgcn_mfma_f32_16x16x32_f16(
                    fa[mi], fb[ni], acc[mi][ni], 0, 0, 0);

        __syncthreads();   // drains vmcnt(0)+lgkmcnt(0): next tile landed,
                           // this tile's LDS reads complete -> buffer reusable
    }

    // epilogue. D layout (verified r4): col = lane&15, row = (lane>>4)*4 + reg
#pragma unroll
    for (int ni = 0; ni < 4; ni++) {
        const int d  = n0 + wc + ni * 16 + l16;
        const float bv = bias[d];
        int s = 0, hh = 0, dh = 0;
        if (MODE == 1) {
            s  = d >> 10;
            hh = (d >> 6) & 15;
            dh = d & 63;
        }
#pragma unroll
        for (int mi = 0; mi < 4; mi++) {
            const int mbase = m0 + wr + mi * 16 + (lane >> 4) * 4;
#pragma unroll
            for (int r = 0; r < 4; r++) {
                const float v = acc[mi][ni][r] + bv;
                const int m = mbase + r;
                if (MODE == 0) {
                    out0[(size_t)m * Ncols + d] = v;
                } else {
                    const int b = m >> 10, n = m & 1023;
                    const size_t bho = (size_t)((b << 4) + hh) << 16;
                    if (s == 0)
                        qg[bho + ((size_t)n << 6) + dh] = (f16)(v * 0.125f);
                    else if (s == 1)
                        kgp[bho + ((size_t)n << 6) + dh] = (f16)v;
                    else
                        vgp[bho + ((size_t)dh << 10) + n] = (f16)v;
                }
            }
        }
    }
    (void)M;
}

// ===========================================================================
// MFMA flash attention (structure verified r6/r8 -- frozen). One block =
// 64 q-rows of one (b,h); 4 waves x 16 q-rows. fp16 MFMA QK^T/PV, fp32
// online softmax. Output plain fp16 O to [B][N][C].
// ===========================================================================
__global__ __launch_bounds__(256, 4)
void attn_mfma(const f16* __restrict__ qf, const f16* __restrict__ kf,
               const f16* __restrict__ vtf, f16* __restrict__ og)
{
    __shared__ f16 Kl[8][64][8];    // [d/8][kcol][8]
    __shared__ f16 Vl[8][64][8];    // [k/8][drow][8]
    __shared__ f16 Pl[4][16][72];   // per-wave P: [wave][qrow][kcol], stride 72

    const int tid  = threadIdx.x;
    const int wid  = tid >> 6;
    const int lane = tid & 63;
    const int l16  = lane & 15;
    const int kg   = lane >> 4;      // 0..3
    const int bh   = blockIdx.y;
    const int q0   = blockIdx.x << 6;

    const size_t bhoff = (size_t)bh << 16;   // bh * 1024 * 64
    const f16* qb = qf  + bhoff;
    const f16* kb = kf  + bhoff;
    const f16* vb = vtf + bhoff;

    // Q fragments: row = q0+wid*16+l16, d = kg*8 + j (+32 for second half)
    f16x8 qfr[2];
    {
        const f16* qrow = qb + ((size_t)(q0 + wid * 16 + l16) << 6);
        qfr[0] = *(const f16x8*)(qrow + kg * 8);
        qfr[1] = *(const f16x8*)(qrow + 32 + kg * 8);
    }

    // staging assignment: 512 chunks of 16B per buffer, 2 per thread
    const int c0 = tid,        col0 = c0 & 63, slot0 = c0 >> 6;
    const int c1 = tid + 256,  col1 = c1 & 63, slot1 = c1 >> 6;

    float mrow[4], lrow[4];
    f32x4 accO[4];
#pragma unroll
    for (int r = 0; r < 4; r++) { mrow[r] = -INFINITY; lrow[r] = 0.f; }
#pragma unroll
    for (int t = 0; t < 4; t++) accO[t] = (f32x4)0.f;

    // prologue: k-tile 0 loads
    f16x8 rk0 = *(const f16x8*)(kb + ((size_t)col0 << 6) + slot0 * 8);
    f16x8 rk1 = *(const f16x8*)(kb + ((size_t)col1 << 6) + slot1 * 8);
    f16x8 rv0 = *(const f16x8*)(vb + ((size_t)col0 << 10) + slot0 * 8);
    f16x8 rv1 = *(const f16x8*)(vb + ((size_t)col1 << 10) + slot1 * 8);

    for (int kt = 0; kt < 16; kt++) {
        __syncthreads();   // previous iter's K/V fragment reads complete
        *(f16x8*)&Kl[slot0][col0][0] = rk0;
        *(f16x8*)&Kl[slot1][col1][0] = rk1;
        *(f16x8*)&Vl[slot0][col0][0] = rv0;
        *(f16x8*)&Vl[slot1][col1][0] = rv1;
        __syncthreads();

        // issue next tile's global loads; latency hides under compute
        if (kt < 15) {
            const int n1 = (kt + 1) << 6;
            rk0 = *(const f16x8*)(kb + ((size_t)(n1 + col0) << 6) + slot0 * 8);
            rk1 = *(const f16x8*)(kb + ((size_t)(n1 + col1) << 6) + slot1 * 8);
            rv0 = *(const f16x8*)(vb + ((size_t)col0 << 10) + n1 + slot0 * 8);
            rv1 = *(const f16x8*)(vb + ((size_t)col1 << 10) + n1 + slot1 * 8);
        }

        // ---- QK^T: wave's 16 rows x 64 cols, 4 col-tiles x 2 d-halves ----
        f32x4 accS[4];
#pragma unroll
        for (int t = 0; t < 4; t++) accS[t] = (f32x4)0.f;
#pragma unroll
        for (int t = 0; t < 4; t++) {
            const f16x8 kf0 = *(const f16x8*)&Kl[kg][t * 16 + l16][0];
            const f16x8 kf1 = *(const f16x8*)&Kl[4 + kg][t * 16 + l16][0];
            accS[t] = __builtin_amdgcn_mfma_f32_16x16x32_f16(qfr[0], kf0, accS[t], 0, 0, 0);
            accS[t] = __builtin_amdgcn_mfma_f32_16x16x32_f16(qfr[1], kf1, accS[t], 0, 0, 0);
        }

        // ---- online softmax; rows r -> q-row 4*kg + r, register-local ----
#pragma unroll
        for (int r = 0; r < 4; r++) {
            float sm = fmaxf(fmaxf(accS[0][r], accS[1][r]),
                             fmaxf(accS[2][r], accS[3][r]));
            sm = fmaxf(sm, __shfl_xor(sm, 1, 16));
            sm = fmaxf(sm, __shfl_xor(sm, 2, 16));
            sm = fmaxf(sm, __shfl_xor(sm, 4, 16));
            sm = fmaxf(sm, __shfl_xor(sm, 8, 16));
            const float mn = fmaxf(mrow[r], sm);
            const float al = __expf(mrow[r] - mn);
            float p0 = __expf(accS[0][r] - mn);
            float p1 = __expf(accS[1][r] - mn);
            float p2 = __expf(accS[2][r] - mn);
            float p3 = __expf(accS[3][r] - mn);
            float rs = (p0 + p1) + (p2 + p3);
            rs += __shfl_xor(rs, 1, 16);
            rs += __shfl_xor(rs, 2, 16);
            rs += __shfl_xor(rs, 4, 16);
            rs += __shfl_xor(rs, 8, 16);
            lrow[r] = lrow[r] * al + rs;
            mrow[r] = mn;
            accO[0][r] *= al;
            accO[1][r] *= al;
            accO[2][r] *= al;
            accO[3][r] *= al;
            const int prow = kg * 4 + r;
            Pl[wid][prow][l16]      = (f16)p0;
            Pl[wid][prow][16 + l16] = (f16)p1;
            Pl[wid][prow][32 + l16] = (f16)p2;
            Pl[wid][prow][48 + l16] = (f16)p3;
        }

        // ---- PV: O(16x64) += P(16x64) * V(64x64), via Vt fragments ----
#pragma unroll
        for (int h = 0; h < 2; h++) {
            const f16x8 pa = *(const f16x8*)&Pl[wid][l16][h * 32 + kg * 8];
#pragma unroll
            for (int t = 0; t < 4; t++) {
                const f16x8 vf = *(const f16x8*)&Vl[h * 4 + kg][t * 16 + l16][0];
                accO[t] = __builtin_amdgcn_mfma_f32_16x16x32_f16(pa, vf, accO[t], 0, 0, 0);
            }
        }
    }

    // ---- epilogue: normalize, fp16 store to [B][N][C] ----
    const int b = bh >> 4, hh = bh & 15;
#pragma unroll
    for (int r = 0; r < 4; r++) {
        const float inv = 1.0f / lrow[r];
        const int n = q0 + wid * 16 + kg * 4 + r;
        const size_t base = ((((size_t)b << 10) + n) << 10) + hh * 64;
#pragma unroll
        for (int t = 0; t < 4; t++)
            og[base + t * 16 + l16] = (f16)(accO[t][r] * inv);
    }
}

// ===========================================================================
// Fallback fp32 path (baseline, audited) — used only if ws_size < 96MB.
// ===========================================================================
#define TILE 128
#define KB   16
#define LSTR (TILE + 4)

template<int MODE>
__global__ __launch_bounds__(256, 2)
void gemm_bt(const float* __restrict__ A, const float* __restrict__ Bm,
             const float* __restrict__ bias, float* __restrict__ out0,
             float* __restrict__ qg, float* __restrict__ kg, float* __restrict__ vg,
             int M, int Ncols, int K)
{
    __shared__ float As[KB][LSTR];
    __shared__ float Bs[KB][LSTR];

    const int tid = threadIdx.x;
    const int tr  = tid >> 4;
    const int tc  = tid & 15;
    const int m0  = blockIdx.y * TILE;
    const int n0  = blockIdx.x * TILE;

    const int lrow = tid >> 2;
    const int lcol = (tid & 3) << 2;

    const float* Ap = A  + (size_t)(m0 + lrow) * K + lcol;
    const float* Bp = Bm + (size_t)(n0 + lrow) * K + lcol;
    const size_t rstep = (size_t)64 * K;

    float acc[8][8];
#pragma unroll
    for (int i = 0; i < 8; i++)
#pragma unroll
        for (int j = 0; j < 8; j++) acc[i][j] = 0.f;

    for (int kt = 0; kt < K; kt += KB) {
        float4 a0 = *(const float4*)(Ap + kt);
        float4 a1 = *(const float4*)(Ap + rstep + kt);
        float4 b0 = *(const float4*)(Bp + kt);
        float4 b1 = *(const float4*)(Bp + rstep + kt);
        __syncthreads();
        As[lcol + 0][lrow]      = a0.x;
        As[lcol + 1][lrow]      = a0.y;
        As[lcol + 2][lrow]      = a0.z;
        As[lcol + 3][lrow]      = a0.w;
        As[lcol + 0][lrow + 64] = a1.x;
        As[lcol + 1][lrow + 64] = a1.y;
        As[lcol + 2][lrow + 64] = a1.z;
        As[lcol + 3][lrow + 64] = a1.w;
        Bs[lcol + 0][lrow]      = b0.x;
        Bs[lcol + 1][lrow]      = b0.y;
        Bs[lcol + 2][lrow]      = b0.z;
        Bs[lcol + 3][lrow]      = b0.w;
        Bs[lcol + 0][lrow + 64] = b1.x;
        Bs[lcol + 1][lrow + 64] = b1.y;
        Bs[lcol + 2][lrow + 64] = b1.z;
        Bs[lcol + 3][lrow + 64] = b1.w;
        __syncthreads();
#pragma unroll
        for (int kk = 0; kk < KB; kk++) {
            float ar[8], br[8];
            *(float4*)&ar[0] = *(const float4*)&As[kk][tr << 2];
            *(float4*)&ar[4] = *(const float4*)&As[kk][64 + (tr << 2)];
            *(float4*)&br[0] = *(const float4*)&Bs[kk][tc << 2];
            *(float4*)&br[4] = *(const float4*)&Bs[kk][64 + (tc << 2)];
#pragma unroll
            for (int i = 0; i < 8; i++)
#pragma unroll
                for (int j = 0; j < 8; j++)
                    acc[i][j] = fmaf(ar[i], br[j], acc[i][j]);
        }
    }

#pragma unroll
    for (int rg = 0; rg < 2; rg++) {
#pragma unroll
        for (int ri = 0; ri < 4; ri++) {
            const int m = m0 + rg * 64 + (tr << 2) + ri;
#pragma unroll
            for (int cg = 0; cg < 2; cg++) {
                const int d = n0 + cg * 64 + (tc << 2);
                const float4 bb = *(const float4*)&bias[d];
                float v0 = acc[rg * 4 + ri][cg * 4 + 0] + bb.x;
                float v1 = acc[rg * 4 + ri][cg * 4 + 1] + bb.y;
                float v2 = acc[rg * 4 + ri][cg * 4 + 2] + bb.z;
                float v3 = acc[rg * 4 + ri][cg * 4 + 3] + bb.w;
                if (MODE == 0) {
                    *(float4*)&out0[(size_t)m * Ncols + d] = make_float4(v0, v1, v2, v3);
                } else {
                    const int s  = d >> 10;
                    const int h  = (d >> 6) & 15;
                    const int dh = d & 63;
                    const int b  = m >> 10;
                    const int n  = m & 1023;
                    float* dst = (s == 0) ? qg : ((s == 1) ? kg : vg);
                    if (s == 0) { v0 *= 0.125f; v1 *= 0.125f; v2 *= 0.125f; v3 *= 0.125f; }
                    const size_t idx = (((size_t)((b << 4) + h) << 10) + n) * 64 + dh;
                    *(float4*)&dst[idx] = make_float4(v0, v1, v2, v3);
                }
            }
        }
    }
}

__global__ __launch_bounds__(256, 2)
void attn_flash_f32(const float* __restrict__ qg, const float* __restrict__ kg,
                    const float* __restrict__ vg, float* __restrict__ og)
{
    __shared__ float Qs[64][68];
    __shared__ float KPs[64][68];
    __shared__ float Vs[64][68];

    const int tid = threadIdx.x;
    const int tr  = tid >> 4;
    const int tc  = tid & 15;
    const int bh  = blockIdx.y;
    const int q0  = blockIdx.x << 6;

    const float* qb = qg + ((size_t)bh * SEQ + q0) * DHEAD;
    const float* kb = kg + (size_t)bh * SEQ * DHEAD;
    const float* vb = vg + (size_t)bh * SEQ * DHEAD;

    const int lr = tid >> 4;
    const int lc = (tid & 15) << 2;

#pragma unroll
    for (int i = 0; i < 4; i++) {
        const int r = lr + (i << 4);
        float4 t = *(const float4*)(qb + r * 64 + lc);
        Qs[lc + 0][r] = t.x;
        Qs[lc + 1][r] = t.y;
        Qs[lc + 2][r] = t.z;
        Qs[lc + 3][r] = t.w;
    }

    float m[4], l[4], acc[4][4];
#pragma unroll
    for (int i = 0; i < 4; i++) {
        m[i] = -INFINITY; l[i] = 0.f;
#pragma unroll
        for (int j = 0; j < 4; j++) acc[i][j] = 0.f;
    }

    for (int kt = 0; kt < 16; kt++) {
        __syncthreads();
        const float* kbt = kb + (size_t)(kt << 6) * 64;
        const float* vbt = vb + (size_t)(kt << 6) * 64;
#pragma unroll
        for (int i = 0; i < 4; i++) {
            const int r = lr + (i << 4);
            float4 t = *(const float4*)(kbt + r * 64 + lc);
            KPs[lc + 0][r] = t.x;
            KPs[lc + 1][r] = t.y;
            KPs[lc + 2][r] = t.z;
            KPs[lc + 3][r] = t.w;
            float4 tv = *(const float4*)(vbt + r * 64 + lc);
            *(float4*)&Vs[r][lc] = tv;
        }
        __syncthreads();

        float s[4][4];
#pragma unroll
        for (int i = 0; i < 4; i++)
#pragma unroll
            for (int j = 0; j < 4; j++) s[i][j] = 0.f;
#pragma unroll 4
        for (int d = 0; d < 64; d++) {
            float qa[4], ka[4];
            *(float4*)qa = *(const float4*)&Qs[d][tr << 2];
            *(float4*)ka = *(const float4*)&KPs[d][tc << 2];
#pragma unroll
            for (int ri = 0; ri < 4; ri++)
#pragma unroll
                for (int ci = 0; ci < 4; ci++)
                    s[ri][ci] = fmaf(qa[ri], ka[ci], s[ri][ci]);
        }
        __syncthreads();

#pragma unroll
        for (int ri = 0; ri < 4; ri++) {
            float tm = fmaxf(fmaxf(s[ri][0], s[ri][1]), fmaxf(s[ri][2], s[ri][3]));
            tm = fmaxf(tm, __shfl_xor(tm, 1, 16));
            tm = fmaxf(tm, __shfl_xor(tm, 2, 16));
            tm = fmaxf(tm, __shfl_xor(tm, 4, 16));
            tm = fmaxf(tm, __shfl_xor(tm, 8, 16));
            const float mn = fmaxf(m[ri], tm);
            const float alpha = __expf(m[ri] - mn);
            const float p0 = __expf(s[ri][0] - mn);
            const float p1 = __expf(s[ri][1] - mn);
            const float p2 = __expf(s[ri][2] - mn);
            const float p3 = __expf(s[ri][3] - mn);
            float rs = (p0 + p1) + (p2 + p3);
            rs += __shfl_xor(rs, 1, 16);
            rs += __shfl_xor(rs, 2, 16);
            rs += __shfl_xor(rs, 4, 16);
            rs += __shfl_xor(rs, 8, 16);
            l[ri] = l[ri] * alpha + rs;
            m[ri] = mn;
            acc[ri][0] *= alpha; acc[ri][1] *= alpha;
            acc[ri][2] *= alpha; acc[ri][3] *= alpha;
            *(float4*)&KPs[(tr << 2) + ri][tc << 2] = make_float4(p0, p1, p2, p3);
        }
        __syncthreads();

#pragma unroll 4
        for (int c = 0; c < 64; c += 4) {
            float pr[4][4], vv[4][4];
            *(float4*)pr[0] = *(const float4*)&KPs[(tr << 2) + 0][c];
            *(float4*)pr[1] = *(const float4*)&KPs[(tr << 2) + 1][c];
            *(float4*)pr[2] = *(const float4*)&KPs[(tr << 2) + 2][c];
            *(float4*)pr[3] = *(const float4*)&KPs[(tr << 2) + 3][c];
            *(float4*)vv[0] = *(const float4*)&Vs[c + 0][tc << 2];
            *(float4*)vv[1] = *(const float4*)&Vs[c + 1][tc << 2];
            *(float4*)vv[2] = *(const float4*)&Vs[c + 2][tc << 2];
            *(float4*)vv[3] = *(const float4*)&Vs[c + 3][tc << 2];
#pragma unroll
            for (int ri = 0; ri < 4; ri++)
#pragma unroll
                for (int j = 0; j < 4; j++) {
                    float a = acc[ri][j];
                    a = fmaf(pr[ri][0], vv[0][j], a);
                    a = fmaf(pr[ri][1], vv[1][j], a);
                    a = fmaf(pr[ri][2], vv[2][j], a);
                    a = fmaf(pr[ri][3], vv[3][j], a);
                    acc[ri][j] = a;
                }
        }
    }

    const int b = bh >> 4, h = bh & 15;
#pragma unroll
    for (int ri = 0; ri < 4; ri++) {
        const float inv = 1.0f / l[ri];
        const int n = q0 + (tr << 2) + ri;
        const size_t idx = (((size_t)b * SEQ + n) << 10) + (h << 6) + (tc << 2);
        *(float4*)&og[idx] = make_float4(acc[ri][0] * inv, acc[ri][1] * inv,
                                         acc[ri][2] * inv, acc[ri][3] * inv);
    }
}

// ===========================================================================
extern "C" void kernel_launch(void* const* d_in, const int* in_sizes, int n_in,
                              void* d_out, int out_size, void* d_ws, size_t ws_size,
                              hipStream_t stream)
{
    const float* x     = (const float*)d_in[0];   // [8,1024,1024]
    const float* w_in  = (const float*)d_in[1];   // [3072,1024]
    const float* b_in  = (const float*)d_in[2];   // [3072]
    const float* w_out = (const float*)d_in[3];   // [1024,1024]
    const float* b_out = (const float*)d_in[4];   // [1024]
    float* out = (float*)d_out;                   // [8,1024,1024]
    (void)in_sizes; (void)n_in; (void)out_size;

    const size_t MB  = 1024 * 1024;
    const size_t per = (size_t)BATCH * HEADS * SEQ * DHEAD;  // 8M elements
    const int    M   = BATCH * SEQ;                          // 8192
    char* ws = (char*)d_ws;

    if (ws_size >= 96 * MB) {
        // --- fp16 MFMA path ---
        f16* qf16  = (f16*)(ws + 0 * MB);    // 16MB [BH][N][64]
        f16* kf16  = (f16*)(ws + 16 * MB);   // 16MB [BH][N][64]
        f16* vtf16 = (f16*)(ws + 32 * MB);   // 16MB [BH][64][N]
        f16* xf16  = (f16*)(ws + 48 * MB);   // 16MB (dead after QKV GEMM)
        f16* of16  = xf16;                   // aliased: born after attention
        f16* wif16 = (f16*)(ws + 64 * MB);   // 6MB
        f16* wof16 = (f16*)(ws + 70 * MB);   // 2MB -> 72MB total

        cvt_f16<<<2048, 256, 0, stream>>>(x,     xf16,  (int)(per / 8));
        cvt_f16<<<1024, 256, 0, stream>>>(w_in,  wif16, 3 * CDIM * CDIM / 8);
        cvt_f16<<<512,  256, 0, stream>>>(w_out, wof16, CDIM * CDIM / 8);

        gemm_f16<1><<<dim3(3 * CDIM / 128, M / 128), 256, 0, stream>>>(
            xf16, wif16, b_in, nullptr, qf16, kf16, vtf16, M, 3 * CDIM, CDIM);

        attn_mfma<<<dim3(SEQ / 64, BATCH * HEADS), 256, 0, stream>>>(
            qf16, kf16, vtf16, of16);

        gemm_f16<0><<<dim3(CDIM / 128, M / 128), 256, 0, stream>>>(
            of16, wof16, b_out, out, nullptr, nullptr, nullptr, M, CDIM, CDIM);
    } else {
        // --- fp32 fallback path (128MB) ---
        float* qws = (float*)d_ws;
        float* kws = qws + per;
        float* vws = kws + per;
        float* aws = vws + per;

        gemm_bt<1><<<dim3(3 * CDIM / TILE, M / TILE), 256, 0, stream>>>(
            x, w_in, b_in, nullptr, qws, kws, vws, M, 3 * CDIM, CDIM);

        attn_flash_f32<<<dim3(SEQ / 64, BATCH * HEADS), 256, 0, stream>>>(
            qws, kws, vws, aws);

        gemm_bt<0><<<dim3(CDIM / TILE, M / TILE), 256, 0, stream>>>(
            aws, w_out, b_out, out, nullptr, nullptr, nullptr, M, CDIM, CDIM);
    }
}